// Round 1
// 793.057 us; speedup vs baseline: 1.0104x; 1.0104x over previous
//
#include <hip/hip_runtime.h>

typedef unsigned short u16;
typedef unsigned int   u32;
typedef __attribute__((ext_vector_type(8))) short bf16x8;
typedef __attribute__((ext_vector_type(4))) float f32x4;

#define MFMA16(a, b, c) __builtin_amdgcn_mfma_f32_16x16x32_bf16((a), (b), (c), 0, 0, 0)

__device__ __forceinline__ float bfu(u16 x) { return __uint_as_float(((u32)x) << 16); }
__device__ __forceinline__ u16 f2bf(float f) {
    u32 u = __float_as_uint(f);
    u32 r = u + 0x7fffu + ((u >> 16) & 1u);   // RNE
    return (u16)(r >> 16);
}
__device__ __forceinline__ u32 pk2(float a, float b) {
    return (u32)f2bf(a) | ((u32)f2bf(b) << 16);
}
__device__ __forceinline__ bf16x8 cvt8(float4 a, float4 b) {
    bf16x8 r;
    r[0] = (short)f2bf(a.x); r[1] = (short)f2bf(a.y);
    r[2] = (short)f2bf(a.z); r[3] = (short)f2bf(a.w);
    r[4] = (short)f2bf(b.x); r[5] = (short)f2bf(b.y);
    r[6] = (short)f2bf(b.z); r[7] = (short)f2bf(b.w);
    return r;
}
// async global->LDS, 16B per lane (dest = wave-uniform base + lane*16)
__device__ __forceinline__ void gl_lds16(const void* g, void* l) {
    __builtin_amdgcn_global_load_lds(
        (const __attribute__((address_space(1))) void*)g,
        (__attribute__((address_space(3))) void*)l, 16, 0, 0);
}

struct CvtArgs { const float* src[7]; u16* dst[7]; };

// ---------------------------------------------------------------------------
// Fused launch 1:
//   blocks [0,2048):    z[h][i][j] = sum_c bias[i,j,c]*Wz[c,h]  (MFMA).
//     NEW: bias staged global->LDS via global_load_lds (1KB fully-coalesced
//     per wave-instr) with pre-swizzled source (XOR ((row&7)<<4) involution)
//     so stride-512B ds_read_b128 fragment reads are ~conflict-free.
//     8x64-row chunks accumulate in regs; one LDS transpose; 16B z stores.
//   blocks [2048,2496): fp32->bf16 convert, 7 tensors x 1M elems, 64 blk each
// ---------------------------------------------------------------------------
__global__ __launch_bounds__(256) void zproj_cvt(
    const float* __restrict__ bias, const float* __restrict__ Wz,
    u16* __restrict__ z, CvtArgs ca)
{
    __shared__ __align__(16) char smem[64 * 512];   // 32KB stage; reused as zbuf
    const int t = threadIdx.x;

    if (blockIdx.x >= 2048) {               // ---- convert part ----
        const int blk  = blockIdx.x - 2048;
        const int tsel = blk >> 6;
        const float* s = ca.src[tsel];
        u16* d = ca.dst[tsel];
        const int base = (blk & 63) * 16384;
        #pragma unroll 4
        for (int it = 0; it < 16; ++it) {
            const int idx = base + (it * 256 + t) * 4;
            float4 v = *(const float4*)(s + idx);
            uint2 p;
            p.x = pk2(v.x, v.y);
            p.y = pk2(v.z, v.w);
            *(uint2*)(d + idx) = p;
        }
        return;
    }

    // ---- zproj part ----
    const int lane = t & 63, w = t >> 6;
    const int ln = lane & 15, q4 = lane >> 4;
    const int row0 = blockIdx.x * 512;
    const int sxor = (ln & 7) << 4;         // read-side swizzle for this lane

    bf16x8 bfrag[4];
    #pragma unroll
    for (int kb = 0; kb < 4; ++kb)
        #pragma unroll
        for (int j = 0; j < 8; ++j)
            bfrag[kb][j] = (short)f2bf(Wz[(kb * 32 + q4 * 8 + j) * 16 + ln]);

    f32x4 c[8];
    const char* gb = (const char*)(bias + (size_t)row0 * 128);
    const int rbase = (w * 16 + ln) * 512;  // local-row byte base in stage

    #pragma unroll
    for (int ch = 0; ch < 8; ++ch) {
        const char* gsrc = gb + ch * (64 * 512);
        // stage 64 rows x 512B: LDS[o] <- global[o ^ ((row&7)<<4)]
        #pragma unroll
        for (int cc = 0; cc < 8; ++cc) {
            const int o   = (w * 8 + cc) * 1024 + lane * 16;
            const int src = o ^ (((o >> 9) & 7) << 4);
            gl_lds16(gsrc + src, smem + (w * 8 + cc) * 1024);
        }
        __syncthreads();
        f32x4 acc = {0, 0, 0, 0};
        #pragma unroll
        for (int kb = 0; kb < 4; ++kb) {
            const int p = rbase + kb * 128 + q4 * 32;
            float4 x0 = *(const float4*)(smem + ((p     ) ^ sxor));
            float4 x1 = *(const float4*)(smem + ((p + 16) ^ sxor));
            acc = MFMA16(cvt8(x0, x1), bfrag[kb], acc);
        }
        c[ch] = acc;
        __syncthreads();
    }

    // transpose via zbuf u16 [16][520] (pad keeps 16B alignment per row)
    u16* zbuf = (u16*)smem;
    #pragma unroll
    for (int ch = 0; ch < 8; ++ch)
        #pragma unroll
        for (int r = 0; r < 4; ++r)
            zbuf[ln * 520 + ch * 64 + w * 16 + q4 * 4 + r] = f2bf(c[ch][r]);
    __syncthreads();

    // coalesced 16B stores: thread t -> h = t>>4, cols (t&15)*32 .. +32
    {
        const int hh = t >> 4, c0 = (t & 15) * 32;
        u16* zg = z + (size_t)hh * 1048576 + row0 + c0;
        const u16* zs = zbuf + hh * 520 + c0;
        #pragma unroll
        for (int n = 0; n < 4; ++n)
            *(uint4*)(zg + n * 8) = *(const uint4*)(zs + n * 8);
    }
}

// ---------------------------------------------------------------------------
// Merged QKVG GEMM (grid 32x16x2 = 1024 blocks, 4 blocks/CU):
//  z=0: A=s_bf16,   W=[Wq|Wg]: n<1024 -> q (bias, bf16); else g (sigmoid, bf16)
//  z=1: A=kin_bf16, W=[Wk|Wv]: n<1024 -> k (bf16);      else vT (bf16 transp.)
// 64x64 tile, BK=64, global_load_lds staging (m97 pattern).
// ---------------------------------------------------------------------------
__global__ __launch_bounds__(256) void gemm_qkvg(
    const u16* __restrict__ sb, const u16* __restrict__ kbf,
    const u16* __restrict__ Wqb, const u16* __restrict__ Wgb,
    const u16* __restrict__ Wkb, const u16* __restrict__ Wvb,
    const float* __restrict__ bqv,
    u16* __restrict__ q, u16* __restrict__ g,
    u16* __restrict__ kk, u16* __restrict__ vT)
{
    __shared__ u16 lA[64 * 64];
    __shared__ u16 lB[64 * 64];
    const int zb = blockIdx.z;
    const u16* Ab = zb ? kbf : sb;
    const u16* W0 = zb ? Wkb : Wqb;
    const u16* W1 = zb ? Wvb : Wgb;

    const int t = threadIdx.x, lane = t & 63, w = t >> 6;
    const int ln = lane & 15, q4 = lane >> 4;
    const int wm = (w & 1) * 32, wn = (w >> 1) * 32;
    const int m0 = blockIdx.y * 64, n0 = blockIdx.x * 64;

    const u16* Wp = (n0 < 1024) ? (W0 + (size_t)n0 * 1024)
                                : (W1 + (size_t)(n0 - 1024) * 1024);
    const int srow = t >> 3, scol = (t & 7) * 8;
    const u16* ga = Ab + (m0 + srow) * 1024 + scol;
    const u16* gb = Wp + srow * 1024 + scol;
    u16* la = lA + t * 8;
    u16* lb = lB + t * 8;

    f32x4 acc00 = {0,0,0,0}, acc01 = {0,0,0,0}, acc10 = {0,0,0,0}, acc11 = {0,0,0,0};

    for (int k0 = 0; k0 < 1024; k0 += 64) {
        gl_lds16(ga + k0,             la);
        gl_lds16(ga + k0 + 32 * 1024, la + 32 * 64);
        gl_lds16(gb + k0,             lb);
        gl_lds16(gb + k0 + 32 * 1024, lb + 32 * 64);
        __syncthreads();
        #pragma unroll
        for (int ks = 0; ks < 2; ++ks) {
            bf16x8 a0 = *(const bf16x8*)(lA + (wm +      ln) * 64 + ks * 32 + q4 * 8);
            bf16x8 a1 = *(const bf16x8*)(lA + (wm + 16 + ln) * 64 + ks * 32 + q4 * 8);
            bf16x8 b0 = *(const bf16x8*)(lB + (wn +      ln) * 64 + ks * 32 + q4 * 8);
            bf16x8 b1 = *(const bf16x8*)(lB + (wn + 16 + ln) * 64 + ks * 32 + q4 * 8);
            acc00 = MFMA16(a0, b0, acc00);
            acc01 = MFMA16(a0, b1, acc01);
            acc10 = MFMA16(a1, b0, acc10);
            acc11 = MFMA16(a1, b1, acc11);
        }
        __syncthreads();
    }

    #pragma unroll
    for (int tm = 0; tm < 2; ++tm) {
        #pragma unroll
        for (int tn = 0; tn < 2; ++tn) {
            const f32x4 a = (tm == 0) ? (tn == 0 ? acc00 : acc01)
                                      : (tn == 0 ? acc10 : acc11);
            #pragma unroll
            for (int r = 0; r < 4; ++r) {
                const int gm = m0 + wm + tm * 16 + q4 * 4 + r;
                const int gn = n0 + wn + tn * 16 + ln;
                float cv = a[r];
                if (zb == 0) {
                    if (gn < 1024) q[gm * 1024 + gn] = f2bf(cv + bqv[gn]);
                    else g[gm * 1024 + gn - 1024] = f2bf(1.0f / (1.0f + __expf(-cv)));
                } else {
                    if (gn < 1024) kk[gm * 1024 + gn] = f2bf(cv);
                    else vT[(gn - 1024) * 1024 + gm] = f2bf(cv);
                }
            }
        }
    }
}

// ---------------------------------------------------------------------------
// Attention: one block = (h, 16-row i-tile). QK^T via MFMA, softmax in regs,
// P -> bf16 LDS (stride 1032), PV via MFMA; epilogue applies sigmoid gate.
// NEW: the 32KB z i-slab is bulk-staged into LDS via global_load_lds
// (coalesced 1KB/instr, XOR-swizzled) replacing per-element 2B global loads.
// The slab shares LDS bytes with pbf (disjoint in time; two barriers apart).
// ---------------------------------------------------------------------------
__global__ __launch_bounds__(256) void attn_kernel(
    const u16* __restrict__ qb, const u16* __restrict__ kmat,
    const u16* __restrict__ vT, const u16* __restrict__ zb,
    const float* __restrict__ maskb, const u16* __restrict__ gmat,
    u16* __restrict__ o)
{
    __shared__ __align__(16) char smem[16 * 1032 * 2];  // 33024B: z-slab then pbf
    __shared__ float redm[4][16];
    __shared__ float reds[4][16];
    const int h = blockIdx.y;
    const int i0 = blockIdx.x * 16;
    const int t = threadIdx.x, lane = t & 63, w = t >> 6;
    const int ln = lane & 15, q4 = lane >> 4;

    // stage z slab [16 i-rows][1024 j] u16 (32KB contiguous in global):
    // LDS[o] <- slab[row*2048 + ((o&2047) ^ ((row&7)<<4))], row = o>>11
    {
        const char* zsl = (const char*)(zb + (size_t)h * 1048576 + (size_t)i0 * 1024);
        #pragma unroll
        for (int cc = 0; cc < 8; ++cc) {
            const int o_  = (w * 8 + cc) * 1024 + lane * 16;
            const int src = (o_ & ~2047) + ((o_ & 2047) ^ (((o_ >> 11) & 7) << 4));
            gl_lds16(zsl + src, smem + (w * 8 + cc) * 1024);
        }
    }

    const u16* qp = qb + (i0 + ln) * 1024 + h * 64 + q4 * 8;
    const bf16x8 aq0 = *(const bf16x8*)(qp);
    const bf16x8 aq1 = *(const bf16x8*)(qp + 32);

    __syncthreads();   // z slab ready

    f32x4 s[16];
    #pragma unroll
    for (int u = 0; u < 16; ++u) {
        const int j0 = (w * 16 + u) * 16;
        const u16* kp = kmat + (j0 + ln) * 1024 + h * 64 + q4 * 8;
        bf16x8 b0 = *(const bf16x8*)(kp);
        bf16x8 b1 = *(const bf16x8*)(kp + 32);
        f32x4 c = {0, 0, 0, 0};
        c = MFMA16(aq0, b0, c);
        c = MFMA16(aq1, b1, c);
        const int j = j0 + ln;
        const float mt = (1.0f - maskb[j]) * (-1000000.0f);
        const int cb = (j0 + ln) * 2;
        #pragma unroll
        for (int r = 0; r < 4; ++r) {
            const int row = q4 * 4 + r;
            const u16 zv = *(const u16*)(smem + row * 2048 + (cb ^ ((row & 7) << 4)));
            c[r] = c[r] * 0.125f + bfu(zv) + mt;
        }
        s[u] = c;
    }

    float mx[4];
    #pragma unroll
    for (int r = 0; r < 4; ++r) {
        float m_ = s[0][r];
        #pragma unroll
        for (int u = 1; u < 16; ++u) m_ = fmaxf(m_, s[u][r]);
        #pragma unroll
        for (int off = 1; off < 16; off <<= 1) m_ = fmaxf(m_, __shfl_xor(m_, off));
        mx[r] = m_;
    }
    if (ln == 0) {
        #pragma unroll
        for (int r = 0; r < 4; ++r) redm[w][q4 * 4 + r] = mx[r];
    }
    __syncthreads();

    float inv[4];
    #pragma unroll
    for (int r = 0; r < 4; ++r) {
        const int row = q4 * 4 + r;
        const float m_ = fmaxf(fmaxf(redm[0][row], redm[1][row]),
                               fmaxf(redm[2][row], redm[3][row]));
        float s_ = 0.f;
        #pragma unroll
        for (int u = 0; u < 16; ++u) {
            float e = __expf(s[u][r] - m_);
            s[u][r] = e;
            s_ += e;
        }
        #pragma unroll
        for (int off = 1; off < 16; off <<= 1) s_ += __shfl_xor(s_, off);
        mx[r] = s_;
    }
    if (ln == 0) {
        #pragma unroll
        for (int r = 0; r < 4; ++r) reds[w][q4 * 4 + r] = mx[r];
    }
    __syncthreads();
    #pragma unroll
    for (int r = 0; r < 4; ++r) {
        const int row = q4 * 4 + r;
        inv[r] = 1.0f / (reds[0][row] + reds[1][row] + reds[2][row] + reds[3][row]);
    }

    u16* pbf = (u16*)smem;   // reuses z-slab bytes (z fully consumed; 2 barriers ago)
    #pragma unroll
    for (int u = 0; u < 16; ++u) {
        const int j0 = (w * 16 + u) * 16;
        #pragma unroll
        for (int r = 0; r < 4; ++r)
            pbf[(q4 * 4 + r) * 1032 + j0 + ln] = f2bf(s[u][r] * inv[r]);
    }
    __syncthreads();

    f32x4 oc = {0, 0, 0, 0};
    #pragma unroll 4
    for (int ks = 0; ks < 32; ++ks) {
        bf16x8 pa = *(const bf16x8*)(pbf + ln * 1032 + ks * 32 + q4 * 8);
        bf16x8 vb = *(const bf16x8*)(vT + (h * 64 + w * 16 + ln) * 1024 + ks * 32 + q4 * 8);
        oc = MFMA16(pa, vb, oc);
    }
    const int col = h * 64 + w * 16 + ln;
    #pragma unroll
    for (int r = 0; r < 4; ++r) {
        const int gi = i0 + q4 * 4 + r;
        const float gv = bfu(gmat[gi * 1024 + col]);
        o[gi * 1024 + col] = f2bf(oc[r] * gv);
    }
}

// ---------------------------------------------------------------------------
// Final GEMM, split-K=4: partial[kz][m][n] = sum_{k in quarter} og[m,k]*Wo[n,k]
// grid (16,16,4) = 1024 blocks. fp32 partials; reduced by reduce4.
// ---------------------------------------------------------------------------
__global__ __launch_bounds__(256) void gemm_out_sk(
    const u16* __restrict__ og, const u16* __restrict__ Wob, float* __restrict__ pbuf)
{
    __shared__ u16 lA[64 * 64];
    __shared__ u16 lB[64 * 64];
    const int t = threadIdx.x, lane = t & 63, w = t >> 6;
    const int ln = lane & 15, q4 = lane >> 4;
    const int wm = (w & 1) * 32, wn = (w >> 1) * 32;
    const int m0 = blockIdx.y * 64, n0 = blockIdx.x * 64;
    const int kz = blockIdx.z;

    const int srow = t >> 3, scol = (t & 7) * 8;
    const u16* ga = og  + (m0 + srow) * 1024 + scol + kz * 256;
    const u16* gb = Wob + (n0 + srow) * 1024 + scol + kz * 256;
    u16* la = lA + t * 8;
    u16* lb = lB + t * 8;

    f32x4 acc00 = {0,0,0,0}, acc01 = {0,0,0,0}, acc10 = {0,0,0,0}, acc11 = {0,0,0,0};

    for (int k0 = 0; k0 < 256; k0 += 64) {
        gl_lds16(ga + k0,             la);
        gl_lds16(ga + k0 + 32 * 1024, la + 32 * 64);
        gl_lds16(gb + k0,             lb);
        gl_lds16(gb + k0 + 32 * 1024, lb + 32 * 64);
        __syncthreads();
        #pragma unroll
        for (int ks = 0; ks < 2; ++ks) {
            bf16x8 a0 = *(const bf16x8*)(lA + (wm +      ln) * 64 + ks * 32 + q4 * 8);
            bf16x8 a1 = *(const bf16x8*)(lA + (wm + 16 + ln) * 64 + ks * 32 + q4 * 8);
            bf16x8 b0 = *(const bf16x8*)(lB + (wn +      ln) * 64 + ks * 32 + q4 * 8);
            bf16x8 b1 = *(const bf16x8*)(lB + (wn + 16 + ln) * 64 + ks * 32 + q4 * 8);
            acc00 = MFMA16(a0, b0, acc00);
            acc01 = MFMA16(a0, b1, acc01);
            acc10 = MFMA16(a1, b0, acc10);
            acc11 = MFMA16(a1, b1, acc11);
        }
        __syncthreads();
    }

    float* pz = pbuf + (size_t)kz * 1048576;
    #pragma unroll
    for (int tm = 0; tm < 2; ++tm) {
        #pragma unroll
        for (int tn = 0; tn < 2; ++tn) {
            const f32x4 a = (tm == 0) ? (tn == 0 ? acc00 : acc01)
                                      : (tn == 0 ? acc10 : acc11);
            #pragma unroll
            for (int r = 0; r < 4; ++r) {
                const int gm = m0 + wm + tm * 16 + q4 * 4 + r;
                const int gn = n0 + wn + tn * 16 + ln;
                pz[gm * 1024 + gn] = a[r];
            }
        }
    }
}

__global__ __launch_bounds__(256) void reduce4(
    const float* __restrict__ p, float* __restrict__ out)
{
    const int idx = (blockIdx.x * 256 + threadIdx.x) * 4;
    float4 a = *(const float4*)(p + idx);
    float4 b = *(const float4*)(p + 1048576 + idx);
    float4 c = *(const float4*)(p + 2097152 + idx);
    float4 d = *(const float4*)(p + 3145728 + idx);
    float4 r;
    r.x = (a.x + b.x) + (c.x + d.x);
    r.y = (a.y + b.y) + (c.y + d.y);
    r.z = (a.z + b.z) + (c.z + d.z);
    r.w = (a.w + b.w) + (c.w + d.w);
    *(float4*)(out + idx) = r;
}

// ---------------------------------------------------------------------------
extern "C" void kernel_launch(void* const* d_in, const int* in_sizes, int n_in,
                              void* d_out, int out_size, void* d_ws, size_t ws_size,
                              hipStream_t stream)
{
    const float* s_in = (const float*)d_in[0];
    const float* k_in = (const float*)d_in[1];
    const float* mask = (const float*)d_in[2];
    const float* bias = (const float*)d_in[3];
    const float* Wq   = (const float*)d_in[4];
    const float* bq   = (const float*)d_in[5];
    const float* Wk   = (const float*)d_in[6];
    const float* Wv   = (const float*)d_in[7];
    const float* Wg   = (const float*)d_in[8];
    const float* Wo   = (const float*)d_in[9];
    const float* Wz   = (const float*)d_in[10];

    char* ws = (char*)d_ws;
    const size_t MB = 1 << 20;
    u16* sb  = (u16*)(ws + 0 * MB);
    u16* kbf = (u16*)(ws + 2 * MB);
    u16* Wqb = (u16*)(ws + 4 * MB);
    u16* Wkb = (u16*)(ws + 6 * MB);
    u16* Wvb = (u16*)(ws + 8 * MB);
    u16* Wgb = (u16*)(ws + 10 * MB);
    u16* Wob = (u16*)(ws + 12 * MB);
    u16* q   = (u16*)(ws + 14 * MB);   // bf16 [i][h*64+d]
    u16* kk  = (u16*)(ws + 16 * MB);   // bf16 [j][h*64+d]
    u16* vT  = (u16*)(ws + 18 * MB);   // bf16 [h*64+d][j]
    u16* g   = (u16*)(ws + 20 * MB);   // bf16 sigmoid gate
    u16* og  = (u16*)(ws + 22 * MB);   // bf16 gated attention output
    u16* z   = (u16*)(ws + 24 * MB);   // bf16 [h][i][j] (32 MB)
    float* pbuf = (float*)(ws + 56 * MB); // fp32 [4][1024][1024] (16 MB)
    float* out = (float*)d_out;

    CvtArgs ca;
    ca.src[0] = s_in; ca.dst[0] = sb;
    ca.src[1] = k_in; ca.dst[1] = kbf;
    ca.src[2] = Wq;   ca.dst[2] = Wqb;
    ca.src[3] = Wk;   ca.dst[3] = Wkb;
    ca.src[4] = Wv;   ca.dst[4] = Wvb;
    ca.src[5] = Wg;   ca.dst[5] = Wgb;
    ca.src[6] = Wo;   ca.dst[6] = Wob;

    const dim3 blk(256);
    hipLaunchKernelGGL(zproj_cvt, dim3(2496), blk, 0, stream, bias, Wz, z, ca);
    hipLaunchKernelGGL(gemm_qkvg, dim3(32, 16, 2), blk, 0, stream,
                       sb, kbf, Wqb, Wgb, Wkb, Wvb, bq, q, g, kk, vT);
    hipLaunchKernelGGL(attn_kernel, dim3(64, 16), blk, 0, stream,
                       q, kk, vT, z, mask, g, og);
    hipLaunchKernelGGL(gemm_out_sk, dim3(16, 16, 4), blk, 0, stream, og, Wob, pbuf);
    hipLaunchKernelGGL(reduce4, dim3(1024), blk, 0, stream, pbuf, out);
}

// Round 2
// 783.070 us; speedup vs baseline: 1.0233x; 1.0128x over previous
//
#include <hip/hip_runtime.h>

typedef unsigned short u16;
typedef unsigned int   u32;
typedef __attribute__((ext_vector_type(8))) short bf16x8;
typedef __attribute__((ext_vector_type(4))) float f32x4;

#define MFMA16(a, b, c) __builtin_amdgcn_mfma_f32_16x16x32_bf16((a), (b), (c), 0, 0, 0)

__device__ __forceinline__ float bfu(u16 x) { return __uint_as_float(((u32)x) << 16); }
__device__ __forceinline__ u16 f2bf(float f) {
    u32 u = __float_as_uint(f);
    u32 r = u + 0x7fffu + ((u >> 16) & 1u);   // RNE
    return (u16)(r >> 16);
}
__device__ __forceinline__ u32 pk2(float a, float b) {
    return (u32)f2bf(a) | ((u32)f2bf(b) << 16);
}
__device__ __forceinline__ bf16x8 cvt8(float4 a, float4 b) {
    bf16x8 r;
    r[0] = (short)f2bf(a.x); r[1] = (short)f2bf(a.y);
    r[2] = (short)f2bf(a.z); r[3] = (short)f2bf(a.w);
    r[4] = (short)f2bf(b.x); r[5] = (short)f2bf(b.y);
    r[6] = (short)f2bf(b.z); r[7] = (short)f2bf(b.w);
    return r;
}
// async global->LDS, 16B per lane (dest = wave-uniform base + lane*16)
__device__ __forceinline__ void gl_lds16(const void* g, void* l) {
    __builtin_amdgcn_global_load_lds(
        (const __attribute__((address_space(1))) void*)g,
        (__attribute__((address_space(3))) void*)l, 16, 0, 0);
}

struct CvtArgs { const float* src[7]; u16* dst[7]; };

// ---------------------------------------------------------------------------
// Kernel 0: fp32->bf16 convert, 7 tensors x 1M elems, 256 blocks per tensor.
// ---------------------------------------------------------------------------
__global__ __launch_bounds__(256) void cvt_kernel(CvtArgs ca)
{
    const int t = threadIdx.x;
    const int blk = blockIdx.x;
    const int tsel = blk >> 8;
    const float* s = ca.src[tsel];
    u16* d = ca.dst[tsel];
    const int base = (blk & 255) * 4096;
    #pragma unroll
    for (int it = 0; it < 4; ++it) {
        const int idx = base + (it * 256 + t) * 4;
        float4 v = *(const float4*)(s + idx);
        uint2 p;
        p.x = pk2(v.x, v.y);
        p.y = pk2(v.z, v.w);
        *(uint2*)(d + idx) = p;
    }
}

// ---------------------------------------------------------------------------
// Kernel 1 (fused, 3072 blocks, interleaved bx%3):
//   bx%3==0 (1024 blocks): merged QKVG GEMM, 64x64 tile, BK=64,
//     T2 XOR-swizzled LDS (pre-swizzled global source, swizzled ds_read),
//     2-phase double-buffered staging.
//   bx%3!=0 (2048 blocks): zproj z[h][i][j] = sum_c bias[i,j,c]*Wz[c,h]
//     (BW-bound 512MB bias read). Interleaving keeps HBM saturated by zproj
//     while qkvg's MFMA runs on co-resident waves.
// ---------------------------------------------------------------------------
__global__ __launch_bounds__(256) void zq_fused(
    const float* __restrict__ bias, const float* __restrict__ Wz,
    u16* __restrict__ z,
    const u16* __restrict__ sb, const u16* __restrict__ kbf,
    const u16* __restrict__ Wqb, const u16* __restrict__ Wgb,
    const u16* __restrict__ Wkb, const u16* __restrict__ Wvb,
    const float* __restrict__ bqv,
    u16* __restrict__ q, u16* __restrict__ g,
    u16* __restrict__ kk, u16* __restrict__ vT)
{
    __shared__ __align__(16) char smem[32768];
    const int bx = blockIdx.x;
    const int bq3 = bx / 3, br3 = bx % 3;
    const int t = threadIdx.x, lane = t & 63, w = t >> 6;
    const int ln = lane & 15, q4 = lane >> 4;

    if (br3 == 0) {
        // ---------------- qkvg block bq3 in [0,1024) ----------------
        const int nb = bq3 & 31, mb = (bq3 >> 5) & 15, zb = bq3 >> 9;
        const u16* Ab = zb ? kbf : sb;
        const u16* W0 = zb ? Wkb : Wqb;
        const u16* W1 = zb ? Wvb : Wgb;
        const int wm = (w & 1) * 32, wn = (w >> 1) * 32;
        const int m0 = mb * 64, n0 = nb * 64;
        const u16* Wp = (n0 < 1024) ? (W0 + (size_t)n0 * 1024)
                                    : (W1 + (size_t)(n0 - 1024) * 1024);
        const int srow = t >> 3;
        const int sunit = ((t & 7) ^ (srow & 7)) * 8;   // swizzled source 16B-unit
        const u16* ga = Ab + (m0 + srow) * 1024 + sunit;
        const u16* gb = Wp + srow * 1024 + sunit;
        const int swz = (ln & 7) << 3;                  // read-side u16 XOR

        u16* const sm16 = (u16*)smem;   // buf c: lA = c*8192, lB = c*8192+4096

        f32x4 acc00 = {0,0,0,0}, acc01 = {0,0,0,0}, acc10 = {0,0,0,0}, acc11 = {0,0,0,0};

        // prologue stage buf0
        {
            u16* la = sm16 + t * 8;
            gl_lds16(ga, la);
            gl_lds16(ga + 32 * 1024, la + 32 * 64);
            gl_lds16(gb, la + 4096);
            gl_lds16(gb + 32 * 1024, la + 4096 + 32 * 64);
        }
        __syncthreads();

        for (int it = 0; it < 16; ++it) {
            const int cur = it & 1;
            if (it < 15) {
                const int kn = (it + 1) * 64;
                u16* la = sm16 + (cur ^ 1) * 8192 + t * 8;
                gl_lds16(ga + kn, la);
                gl_lds16(ga + kn + 32 * 1024, la + 32 * 64);
                gl_lds16(gb + kn, la + 4096);
                gl_lds16(gb + kn + 32 * 1024, la + 4096 + 32 * 64);
            }
            const u16* LA = sm16 + cur * 8192;
            const u16* LB = LA + 4096;
            #pragma unroll
            for (int ks = 0; ks < 2; ++ks) {
                bf16x8 a0 = *(const bf16x8*)(LA + (wm +      ln) * 64 + ((ks * 32 + q4 * 8) ^ swz));
                bf16x8 a1 = *(const bf16x8*)(LA + (wm + 16 + ln) * 64 + ((ks * 32 + q4 * 8) ^ swz));
                bf16x8 b0 = *(const bf16x8*)(LB + (wn +      ln) * 64 + ((ks * 32 + q4 * 8) ^ swz));
                bf16x8 b1 = *(const bf16x8*)(LB + (wn + 16 + ln) * 64 + ((ks * 32 + q4 * 8) ^ swz));
                acc00 = MFMA16(a0, b0, acc00);
                acc01 = MFMA16(a0, b1, acc01);
                acc10 = MFMA16(a1, b0, acc10);
                acc11 = MFMA16(a1, b1, acc11);
            }
            __syncthreads();
        }

        #pragma unroll
        for (int tm = 0; tm < 2; ++tm) {
            #pragma unroll
            for (int tn = 0; tn < 2; ++tn) {
                const f32x4 a = (tm == 0) ? (tn == 0 ? acc00 : acc01)
                                          : (tn == 0 ? acc10 : acc11);
                #pragma unroll
                for (int r = 0; r < 4; ++r) {
                    const int gm = m0 + wm + tm * 16 + q4 * 4 + r;
                    const int gn = n0 + wn + tn * 16 + ln;
                    float cv = a[r];
                    if (zb == 0) {
                        if (gn < 1024) q[gm * 1024 + gn] = f2bf(cv + bqv[gn]);
                        else g[gm * 1024 + gn - 1024] = f2bf(1.0f / (1.0f + __expf(-cv)));
                    } else {
                        if (gn < 1024) kk[gm * 1024 + gn] = f2bf(cv);
                        else vT[(gn - 1024) * 1024 + gm] = f2bf(cv);
                    }
                }
            }
        }
        return;
    }

    // ---------------- zproj block id in [0,2048) ----------------
    const int zid = bq3 * 2 + (br3 - 1);
    const int row0 = zid * 512;
    const int sxor = (ln & 7) << 4;         // read-side byte swizzle

    bf16x8 bfrag[4];
    #pragma unroll
    for (int kb = 0; kb < 4; ++kb)
        #pragma unroll
        for (int j = 0; j < 8; ++j)
            bfrag[kb][j] = (short)f2bf(Wz[(kb * 32 + q4 * 8 + j) * 16 + ln]);

    f32x4 c[8];
    const char* gbp = (const char*)(bias + (size_t)row0 * 128);
    const int rbase = (w * 16 + ln) * 512;  // local-row byte base in stage

    #pragma unroll
    for (int ch = 0; ch < 8; ++ch) {
        const char* gsrc = gbp + ch * (64 * 512);
        // stage 64 rows x 512B: LDS[o] <- global[o ^ ((row&7)<<4)]
        #pragma unroll
        for (int cc = 0; cc < 8; ++cc) {
            const int o   = (w * 8 + cc) * 1024 + lane * 16;
            const int src = o ^ (((o >> 9) & 7) << 4);
            gl_lds16(gsrc + src, smem + (w * 8 + cc) * 1024);
        }
        __syncthreads();
        f32x4 acc = {0, 0, 0, 0};
        #pragma unroll
        for (int kb = 0; kb < 4; ++kb) {
            const int p = rbase + kb * 128 + q4 * 32;
            float4 x0 = *(const float4*)(smem + ((p     ) ^ sxor));
            float4 x1 = *(const float4*)(smem + ((p + 16) ^ sxor));
            acc = MFMA16(cvt8(x0, x1), bfrag[kb], acc);
        }
        c[ch] = acc;
        __syncthreads();
    }

    // transpose via zbuf u16 [16][520]
    u16* zbuf = (u16*)smem;
    #pragma unroll
    for (int ch = 0; ch < 8; ++ch)
        #pragma unroll
        for (int r = 0; r < 4; ++r)
            zbuf[ln * 520 + ch * 64 + w * 16 + q4 * 4 + r] = f2bf(c[ch][r]);
    __syncthreads();

    {
        const int hh = t >> 4, c0 = (t & 15) * 32;
        u16* zg = z + (size_t)hh * 1048576 + row0 + c0;
        const u16* zs = zbuf + hh * 520 + c0;
        #pragma unroll
        for (int n = 0; n < 4; ++n)
            *(uint4*)(zg + n * 8) = *(const uint4*)(zs + n * 8);
    }
}

// ---------------------------------------------------------------------------
// Attention: one block = (h, 16-row i-tile). QK^T via MFMA, softmax in regs,
// z i-slab bulk-staged via global_load_lds (XOR-swizzled), P -> bf16 LDS,
// PV via MFMA; epilogue applies sigmoid gate. (Unchanged this round.)
// ---------------------------------------------------------------------------
__global__ __launch_bounds__(256) void attn_kernel(
    const u16* __restrict__ qb, const u16* __restrict__ kmat,
    const u16* __restrict__ vT, const u16* __restrict__ zb,
    const float* __restrict__ maskb, const u16* __restrict__ gmat,
    u16* __restrict__ o)
{
    __shared__ __align__(16) char smem[16 * 1032 * 2];
    __shared__ float redm[4][16];
    __shared__ float reds[4][16];
    const int h = blockIdx.y;
    const int i0 = blockIdx.x * 16;
    const int t = threadIdx.x, lane = t & 63, w = t >> 6;
    const int ln = lane & 15, q4 = lane >> 4;

    {
        const char* zsl = (const char*)(zb + (size_t)h * 1048576 + (size_t)i0 * 1024);
        #pragma unroll
        for (int cc = 0; cc < 8; ++cc) {
            const int o_  = (w * 8 + cc) * 1024 + lane * 16;
            const int src = (o_ & ~2047) + ((o_ & 2047) ^ (((o_ >> 11) & 7) << 4));
            gl_lds16(zsl + src, smem + (w * 8 + cc) * 1024);
        }
    }

    const u16* qp = qb + (i0 + ln) * 1024 + h * 64 + q4 * 8;
    const bf16x8 aq0 = *(const bf16x8*)(qp);
    const bf16x8 aq1 = *(const bf16x8*)(qp + 32);

    __syncthreads();   // z slab ready

    f32x4 s[16];
    #pragma unroll
    for (int u = 0; u < 16; ++u) {
        const int j0 = (w * 16 + u) * 16;
        const u16* kp = kmat + (j0 + ln) * 1024 + h * 64 + q4 * 8;
        bf16x8 b0 = *(const bf16x8*)(kp);
        bf16x8 b1 = *(const bf16x8*)(kp + 32);
        f32x4 c = {0, 0, 0, 0};
        c = MFMA16(aq0, b0, c);
        c = MFMA16(aq1, b1, c);
        const int j = j0 + ln;
        const float mt = (1.0f - maskb[j]) * (-1000000.0f);
        const int cb = (j0 + ln) * 2;
        #pragma unroll
        for (int r = 0; r < 4; ++r) {
            const int row = q4 * 4 + r;
            const u16 zv = *(const u16*)(smem + row * 2048 + (cb ^ ((row & 7) << 4)));
            c[r] = c[r] * 0.125f + bfu(zv) + mt;
        }
        s[u] = c;
    }

    float mx[4];
    #pragma unroll
    for (int r = 0; r < 4; ++r) {
        float m_ = s[0][r];
        #pragma unroll
        for (int u = 1; u < 16; ++u) m_ = fmaxf(m_, s[u][r]);
        #pragma unroll
        for (int off = 1; off < 16; off <<= 1) m_ = fmaxf(m_, __shfl_xor(m_, off));
        mx[r] = m_;
    }
    if (ln == 0) {
        #pragma unroll
        for (int r = 0; r < 4; ++r) redm[w][q4 * 4 + r] = mx[r];
    }
    __syncthreads();

    float inv[4];
    #pragma unroll
    for (int r = 0; r < 4; ++r) {
        const int row = q4 * 4 + r;
        const float m_ = fmaxf(fmaxf(redm[0][row], redm[1][row]),
                               fmaxf(redm[2][row], redm[3][row]));
        float s_ = 0.f;
        #pragma unroll
        for (int u = 0; u < 16; ++u) {
            float e = __expf(s[u][r] - m_);
            s[u][r] = e;
            s_ += e;
        }
        #pragma unroll
        for (int off = 1; off < 16; off <<= 1) s_ += __shfl_xor(s_, off);
        mx[r] = s_;
    }
    if (ln == 0) {
        #pragma unroll
        for (int r = 0; r < 4; ++r) reds[w][q4 * 4 + r] = mx[r];
    }
    __syncthreads();
    #pragma unroll
    for (int r = 0; r < 4; ++r) {
        const int row = q4 * 4 + r;
        inv[r] = 1.0f / (reds[0][row] + reds[1][row] + reds[2][row] + reds[3][row]);
    }

    u16* pbf = (u16*)smem;
    #pragma unroll
    for (int u = 0; u < 16; ++u) {
        const int j0 = (w * 16 + u) * 16;
        #pragma unroll
        for (int r = 0; r < 4; ++r)
            pbf[(q4 * 4 + r) * 1032 + j0 + ln] = f2bf(s[u][r] * inv[r]);
    }
    __syncthreads();

    f32x4 oc = {0, 0, 0, 0};
    #pragma unroll 4
    for (int ks = 0; ks < 32; ++ks) {
        bf16x8 pa = *(const bf16x8*)(pbf + ln * 1032 + ks * 32 + q4 * 8);
        bf16x8 vb = *(const bf16x8*)(vT + (h * 64 + w * 16 + ln) * 1024 + ks * 32 + q4 * 8);
        oc = MFMA16(pa, vb, oc);
    }
    const int col = h * 64 + w * 16 + ln;
    #pragma unroll
    for (int r = 0; r < 4; ++r) {
        const int gi = i0 + q4 * 4 + r;
        const float gv = bfu(gmat[gi * 1024 + col]);
        o[gi * 1024 + col] = f2bf(oc[r] * gv);
    }
}

// ---------------------------------------------------------------------------
// Final GEMM, direct K=1024 (replaces split-K + reduce4):
// out[m][n] = sum_k og[m,k]*Wo[n,k], fp32 out. grid (16,16), 64x64 tile,
// T2-swizzled LDS, 2-phase double-buffered staging.
// ---------------------------------------------------------------------------
__global__ __launch_bounds__(256) void gemm_out(
    const u16* __restrict__ og, const u16* __restrict__ Wob,
    float* __restrict__ out)
{
    __shared__ __align__(16) char smem[32768];
    const int t = threadIdx.x, lane = t & 63, w = t >> 6;
    const int ln = lane & 15, q4 = lane >> 4;
    const int wm = (w & 1) * 32, wn = (w >> 1) * 32;
    const int m0 = blockIdx.y * 64, n0 = blockIdx.x * 64;

    const int srow = t >> 3;
    const int sunit = ((t & 7) ^ (srow & 7)) * 8;
    const u16* ga = og  + (m0 + srow) * 1024 + sunit;
    const u16* gb = Wob + (n0 + srow) * 1024 + sunit;
    const int swz = (ln & 7) << 3;
    u16* const sm16 = (u16*)smem;

    f32x4 acc00 = {0,0,0,0}, acc01 = {0,0,0,0}, acc10 = {0,0,0,0}, acc11 = {0,0,0,0};

    {
        u16* la = sm16 + t * 8;
        gl_lds16(ga, la);
        gl_lds16(ga + 32 * 1024, la + 32 * 64);
        gl_lds16(gb, la + 4096);
        gl_lds16(gb + 32 * 1024, la + 4096 + 32 * 64);
    }
    __syncthreads();

    for (int it = 0; it < 16; ++it) {
        const int cur = it & 1;
        if (it < 15) {
            const int kn = (it + 1) * 64;
            u16* la = sm16 + (cur ^ 1) * 8192 + t * 8;
            gl_lds16(ga + kn, la);
            gl_lds16(ga + kn + 32 * 1024, la + 32 * 64);
            gl_lds16(gb + kn, la + 4096);
            gl_lds16(gb + kn + 32 * 1024, la + 4096 + 32 * 64);
        }
        const u16* LA = sm16 + cur * 8192;
        const u16* LB = LA + 4096;
        #pragma unroll
        for (int ks = 0; ks < 2; ++ks) {
            bf16x8 a0 = *(const bf16x8*)(LA + (wm +      ln) * 64 + ((ks * 32 + q4 * 8) ^ swz));
            bf16x8 a1 = *(const bf16x8*)(LA + (wm + 16 + ln) * 64 + ((ks * 32 + q4 * 8) ^ swz));
            bf16x8 b0 = *(const bf16x8*)(LB + (wn +      ln) * 64 + ((ks * 32 + q4 * 8) ^ swz));
            bf16x8 b1 = *(const bf16x8*)(LB + (wn + 16 + ln) * 64 + ((ks * 32 + q4 * 8) ^ swz));
            acc00 = MFMA16(a0, b0, acc00);
            acc01 = MFMA16(a0, b1, acc01);
            acc10 = MFMA16(a1, b0, acc10);
            acc11 = MFMA16(a1, b1, acc11);
        }
        __syncthreads();
    }

    #pragma unroll
    for (int tm = 0; tm < 2; ++tm) {
        #pragma unroll
        for (int tn = 0; tn < 2; ++tn) {
            const f32x4 a = (tm == 0) ? (tn == 0 ? acc00 : acc01)
                                      : (tn == 0 ? acc10 : acc11);
            #pragma unroll
            for (int r = 0; r < 4; ++r) {
                const int gm = m0 + wm + tm * 16 + q4 * 4 + r;
                const int gn = n0 + wn + tn * 16 + ln;
                out[gm * 1024 + gn] = a[r];
            }
        }
    }
}

// ---------------------------------------------------------------------------
extern "C" void kernel_launch(void* const* d_in, const int* in_sizes, int n_in,
                              void* d_out, int out_size, void* d_ws, size_t ws_size,
                              hipStream_t stream)
{
    const float* s_in = (const float*)d_in[0];
    const float* k_in = (const float*)d_in[1];
    const float* mask = (const float*)d_in[2];
    const float* bias = (const float*)d_in[3];
    const float* Wq   = (const float*)d_in[4];
    const float* bq   = (const float*)d_in[5];
    const float* Wk   = (const float*)d_in[6];
    const float* Wv   = (const float*)d_in[7];
    const float* Wg   = (const float*)d_in[8];
    const float* Wo   = (const float*)d_in[9];
    const float* Wz   = (const float*)d_in[10];

    char* ws = (char*)d_ws;
    const size_t MB = 1 << 20;
    u16* sb  = (u16*)(ws + 0 * MB);
    u16* kbf = (u16*)(ws + 2 * MB);
    u16* Wqb = (u16*)(ws + 4 * MB);
    u16* Wkb = (u16*)(ws + 6 * MB);
    u16* Wvb = (u16*)(ws + 8 * MB);
    u16* Wgb = (u16*)(ws + 10 * MB);
    u16* Wob = (u16*)(ws + 12 * MB);
    u16* q   = (u16*)(ws + 14 * MB);   // bf16 [i][h*64+d]
    u16* kk  = (u16*)(ws + 16 * MB);   // bf16 [j][h*64+d]
    u16* vT  = (u16*)(ws + 18 * MB);   // bf16 [h*64+d][j]
    u16* g   = (u16*)(ws + 20 * MB);   // bf16 sigmoid gate
    u16* og  = (u16*)(ws + 22 * MB);   // bf16 gated attention output
    u16* z   = (u16*)(ws + 24 * MB);   // bf16 [h][i][j] (32 MB)
    float* out = (float*)d_out;

    CvtArgs ca;
    ca.src[0] = s_in; ca.dst[0] = sb;
    ca.src[1] = k_in; ca.dst[1] = kbf;
    ca.src[2] = Wq;   ca.dst[2] = Wqb;
    ca.src[3] = Wk;   ca.dst[3] = Wkb;
    ca.src[4] = Wv;   ca.dst[4] = Wvb;
    ca.src[5] = Wg;   ca.dst[5] = Wgb;
    ca.src[6] = Wo;   ca.dst[6] = Wob;

    const dim3 blk(256);
    hipLaunchKernelGGL(cvt_kernel, dim3(1792), blk, 0, stream, ca);
    hipLaunchKernelGGL(zq_fused, dim3(3072), blk, 0, stream,
                       bias, Wz, z, sb, kbf, Wqb, Wgb, Wkb, Wvb, bq, q, g, kk, vT);
    hipLaunchKernelGGL(attn_kernel, dim3(64, 16), blk, 0, stream,
                       q, kk, vT, z, mask, g, og);
    hipLaunchKernelGGL(gemm_out, dim3(16, 16), blk, 0, stream, og, Wob, out);
}